// Round 10
// baseline (229.576 us; speedup 1.0000x reference)
//
#include <hip/hip_runtime.h>

// B=8, C=256, H=W=32 -> S=1024; NH=8, DK=256; qkv dim 6144.
#define NH    8
#define DK    256
#define SS    1024
// q is pre-scaled by SCALE*log2(e) in k1 so softmax runs in exp2 domain.
#define QSCALE 0.09016844136947155f   // (1/16) * 1.4426950408889634
#define TSH   8192                    // shorts per 16 KB tile (32 rows x 256 k)

using frag8  = __attribute__((ext_vector_type(8))) short;   // 8 bf16 (4 VGPRs)
using f32x16 = __attribute__((ext_vector_type(16))) float;  // 32x32 MFMA acc

__device__ __forceinline__ unsigned short f2bf(float f) {
    unsigned int u = __float_as_uint(f);
    return (unsigned short)((u + 0x7FFFu + ((u >> 16) & 1u)) >> 16);   // RNE
}
__device__ __forceinline__ unsigned int pk2bf(float lo, float hi) {
    unsigned int ul = __float_as_uint(lo), uh = __float_as_uint(hi);
    ul += 0x7FFFu + ((ul >> 16) & 1u);
    uh += 0x7FFFu + ((uh >> 16) & 1u);
    return (ul >> 16) | (uh & 0xFFFF0000u);
}

// async global->LDS, 16B/lane; LDS dest = wave-uniform base + lane*16.
__device__ __forceinline__ void load_lds16(const void* g, void* l) {
    __builtin_amdgcn_global_load_lds(
        (const __attribute__((address_space(1))) unsigned int*)g,
        (__attribute__((address_space(3))) unsigned int*)l, 16, 0, 0);
}

// T32 format: panel = 32 rows x K cols; cell(row r, kchunk c) = 8 shorts at
// (c*32 + r)*8. Frag reads are 64 consecutive 16B cells (conflict-free).
// q/k: T32 panels (rows=tokens, cols=d). v: key-permuted tiles (chunk g*2+hw,
// position j holds key 16g+4hw+(j&3)+8*(j>>2)). O (over qb): q/k T32 format.

// ---------------------------------------------------------------------------
// K0: x, Wp, Wo  fp32 -> bf16 T32 panels, one launch. (unchanged from r9)
// ---------------------------------------------------------------------------
__global__ __launch_bounds__(256) void k0_all(
    const float* __restrict__ x,  unsigned short* __restrict__ xbT,
    const float* __restrict__ Wp, unsigned short* __restrict__ WptT,
    const float* __restrict__ Wo, unsigned short* __restrict__ WotT)
{
    __shared__ float tile[32][33];
    const int bid = blockIdx.x;
    const float* in; unsigned short* outp; int C, c0, r0; size_t pbase; int psz;
    if (bid < 2048) {            // x[8][256][1024]: k=channel(256), n=s(1024)
        int rr = bid;
        int b = rr >> 8;
        in = x + (size_t)b * 256 * 1024;
        C = 1024; c0 = (rr & 31) * 32; r0 = ((rr >> 5) & 7) * 32;
        psz = 8192; pbase = (size_t)(b * 32 + (c0 >> 5)); outp = xbT;
    } else if (bid < 3584) {     // Wp[256][6144]: k=256, n=6144
        int rr = bid - 2048;
        in = Wp; C = 6144; c0 = (rr % 192) * 32; r0 = (rr / 192) * 32;
        psz = 8192; pbase = (size_t)(c0 >> 5); outp = WptT;
    } else {                     // Wo[2048][256]: k=2048, n=256
        int rr = bid - 3584;
        in = Wo; C = 256; c0 = (rr & 7) * 32; r0 = (rr >> 3) * 32;
        psz = 65536; pbase = (size_t)(c0 >> 5); outp = WotT;
    }
    const int tx = threadIdx.x & 31, ty = threadIdx.x >> 5;
#pragma unroll
    for (int j = 0; j < 4; j++)
        tile[ty + j * 8][tx] = in[(size_t)(r0 + ty + j * 8) * C + c0 + tx];
    __syncthreads();
    const int k = r0 + tx;
    unsigned short* dst = outp + pbase * psz + ((k >> 3) * 32) * 8 + (k & 7);
#pragma unroll
    for (int j = 0; j < 4; j++)
        dst[(ty + j * 8) * 8] = f2bf(tile[tx][ty + j * 8]);
}

// ---------------------------------------------------------------------------
// K1: qkv = xt @ Wp + bp. 32x32x16 MFMA, T32, conflict-free, dbuf,
// 128 qkv-dims x 256 tokens per block (2x MFMA per barrier vs r9).
// q/k: A=Wpt(dims), B=xb(tokens), acc[8 token panels].
// v:   A=xb(tokens), B=Wpt(dims), acc[2 tok][4 dim].
// ---------------------------------------------------------------------------
__global__ __launch_bounds__(256) void k1_qkv(
    const unsigned short* __restrict__ xbT, const unsigned short* __restrict__ WptT,
    const float* __restrict__ bp,
    unsigned short* __restrict__ qb, unsigned short* __restrict__ kb,
    unsigned short* __restrict__ vb)
{
    __shared__ unsigned short Xs[2][8192];   // 8 token panels x 2 KB per kt
    __shared__ unsigned short Ws[2][4096];   // 4 dim panels
    const int t = threadIdx.x;
    const int wave = t >> 6, lane = t & 63;
    const int l32 = lane & 31, hw = lane >> 5;
    const int n0 = blockIdx.x * 128;          // qkv dims
    const int m0 = blockIdx.y * 256;          // tokens
    const int b = m0 >> 10, s0 = m0 & 1023;

    const int h = n0 / 768;
    const int rem = n0 - h * 768;
    const int tt = rem >> 8;                  // 0=q 1=k 2=v (block-uniform)
    const int dcol0 = rem & 255;

    const unsigned short* Xg = xbT + (size_t)(b * 32 + (s0 >> 5)) * TSH;
    const unsigned short* Wg = WptT + (size_t)(n0 >> 5) * TSH;

    f32x16 acc[8];
#pragma unroll
    for (int j = 0; j < 8; j++)
#pragma unroll
        for (int r = 0; r < 16; r++) acc[j][r] = 0.f;

    auto stage = [&](int buf, int kt) {
#pragma unroll
        for (int j = 0; j < 6; j++) {
            int rgn = wave * 6 + j;           // 24 regions of 1 KB
            if (rgn < 16) {
                int p = rgn >> 1, half = rgn & 1;
                load_lds16(Xg + (size_t)p * TSH + kt * 1024 + half * 512 + lane * 8,
                           &Xs[buf][p * 1024 + half * 512]);
            } else {
                int r2 = rgn - 16, p = r2 >> 1, half = r2 & 1;
                load_lds16(Wg + (size_t)p * TSH + kt * 1024 + half * 512 + lane * 8,
                           &Ws[buf][p * 1024 + half * 512]);
            }
        }
    };

    auto body = [&](const unsigned short* Xb, const unsigned short* Wb) {
        if (tt < 2) {
#pragma unroll
            for (int t2 = 0; t2 < 2; t2++) {
                frag8 af = *(const frag8*)(Wb + wave * 1024 + (2 * t2 + hw) * 256 + l32 * 8);
#pragma unroll
                for (int j = 0; j < 8; j++) {
                    frag8 bf = *(const frag8*)(Xb + j * 1024 + (2 * t2 + hw) * 256 + l32 * 8);
                    acc[j] = __builtin_amdgcn_mfma_f32_32x32x16_bf16(af, bf, acc[j], 0, 0, 0);
                }
            }
        } else {
#pragma unroll
            for (int t2 = 0; t2 < 2; t2++) {
                frag8 bfv[4];
#pragma unroll
                for (int j = 0; j < 4; j++)
                    bfv[j] = *(const frag8*)(Wb + j * 1024 + (2 * t2 + hw) * 256 + l32 * 8);
#pragma unroll
                for (int mi = 0; mi < 2; mi++) {
                    frag8 af = *(const frag8*)(Xb + (wave * 2 + mi) * 1024 + (2 * t2 + hw) * 256 + l32 * 8);
#pragma unroll
                    for (int j = 0; j < 4; j++)
                        acc[mi * 4 + j] = __builtin_amdgcn_mfma_f32_32x32x16_bf16(af, bfv[j], acc[mi * 4 + j], 0, 0, 0);
                }
            }
        }
    };

    stage(0, 0);
    __syncthreads();
    for (int kt = 0; kt < 6; kt += 2) {
        stage(1, kt + 1); body(&Xs[0][0], &Ws[0][0]); __syncthreads();
        stage(0, kt + 2); body(&Xs[1][0], &Ws[1][0]); __syncthreads();
    }
    stage(1, 7); body(&Xs[0][0], &Ws[0][0]); __syncthreads();
    body(&Xs[1][0], &Ws[1][0]);

    if (tt < 2) {
        const float sc = (tt == 0) ? QSCALE : 1.0f;
        unsigned short* dst0 = (tt == 0 ? qb : kb);
        const int dc0 = (dcol0 + wave * 32) >> 3;
#pragma unroll
        for (int G = 0; G < 4; G++) {
            float4 bb = *(const float4*)(&bp[n0 + wave * 32 + 4 * hw + 8 * G]);
#pragma unroll
            for (int j = 0; j < 8; j++) {
                unsigned short* cell = dst0
                    + (size_t)((b * NH + h) * 32 + (s0 >> 5) + j) * TSH
                    + ((dc0 + G) * 32 + l32) * 8 + 4 * hw;
                uint2 st;
                st.x = pk2bf((acc[j][4 * G + 0] + bb.x) * sc, (acc[j][4 * G + 1] + bb.y) * sc);
                st.y = pk2bf((acc[j][4 * G + 2] + bb.z) * sc, (acc[j][4 * G + 3] + bb.w) * sc);
                *(uint2*)cell = st;
            }
        }
    } else {
        unsigned short* vt0 = vb + (size_t)((b * NH + h) * 32 + (s0 >> 5)) * TSH;
#pragma unroll
        for (int mi = 0; mi < 2; mi++) {
            unsigned short* vt = vt0 + (size_t)(wave * 2 + mi) * TSH;
#pragma unroll
            for (int j = 0; j < 4; j++) {
                const int d = dcol0 + j * 32 + l32;
                const float bv = bp[n0 + j * 32 + l32];
#pragma unroll
                for (int G = 0; G < 4; G++) {
                    int g = G >> 1;
                    unsigned short* cell = vt + (g * 2 + hw) * 2048 + d * 8 + 4 * (G & 1);
                    uint2 st;
                    st.x = pk2bf(acc[mi * 4 + j][4 * G + 0] + bv, acc[mi * 4 + j][4 * G + 1] + bv);
                    st.y = pk2bf(acc[mi * 4 + j][4 * G + 2] + bv, acc[mi * 4 + j][4 * G + 3] + bv);
                    *(uint2*)cell = st;
                }
            }
        }
    }
}

// ---------------------------------------------------------------------------
// K2: attention (r9 math). K-loop unrolled x2 with compile-time buffer
// pointers (LDS offsets become immediates -> less addr VALU); last iter
// peeled so the loop has no prefetch branch.
// ---------------------------------------------------------------------------
__global__ __launch_bounds__(256, 2) void k2_attn(
    const unsigned short* __restrict__ qb, const unsigned short* __restrict__ kb,
    const unsigned short* __restrict__ vb, unsigned short* __restrict__ ob)
{
    __shared__ unsigned short Ks[2][TSH];
    __shared__ unsigned short Vs[2][TSH];

    const int t = threadIdx.x;
    const int wave = t >> 6, lane = t & 63;
    const int l32 = lane & 31, hw = lane >> 5;

    const int flat = blockIdx.x;
    const int xcd = flat & 7, tt2 = flat >> 3;
    const int qt = tt2 & 7;
    const int bh = xcd * 8 + (tt2 >> 3);

    frag8 qf[16];
    {
        const unsigned short* qp = qb + ((size_t)bh * 32 + qt * 4 + wave) * TSH
                                 + hw * 256 + l32 * 8;
#pragma unroll
        for (int s = 0; s < 16; s++) qf[s] = *(const frag8*)(qp + s * 512);
    }

    f32x16 acc[8];
#pragma unroll
    for (int nb = 0; nb < 8; nb++)
#pragma unroll
        for (int r = 0; r < 16; r++) acc[nb][r] = 0.f;
    float lsum = 0.f;

    // per-lane staging bases (wave's 4 chunks are contiguous 2 KB)
    const unsigned short* kstg = kb + (size_t)bh * 32 * TSH + wave * 2048 + lane * 8;
    const unsigned short* vstg = vb + (size_t)bh * 32 * TSH + wave * 2048 + lane * 8;

    auto prefetch = [&](int buf, int kt) {
#pragma unroll
        for (int j = 0; j < 4; j++) {
            load_lds16(kstg + (size_t)kt * TSH + j * 512, &Ks[buf][wave * 2048 + j * 512]);
            load_lds16(vstg + (size_t)kt * TSH + j * 512, &Vs[buf][wave * 2048 + j * 512]);
        }
    };

    auto body = [&](const unsigned short* Kb, const unsigned short* Vb) {
        f32x16 sa0, sa1;
#pragma unroll
        for (int r = 0; r < 16; r++) { sa0[r] = 0.f; sa1[r] = 0.f; }
#pragma unroll
        for (int s = 0; s < 16; s += 2) {
            frag8 kf0 = *(const frag8*)(Kb + (2 * s + hw) * 256 + l32 * 8);
            frag8 kf1 = *(const frag8*)(Kb + (2 * s + 2 + hw) * 256 + l32 * 8);
            sa0 = __builtin_amdgcn_mfma_f32_32x32x16_bf16(kf0, qf[s], sa0, 0, 0, 0);
            sa1 = __builtin_amdgcn_mfma_f32_32x32x16_bf16(kf1, qf[s + 1], sa1, 0, 0, 0);
        }
        float p[16];
#pragma unroll
        for (int e = 0; e < 16; e++) {
            p[e] = exp2f(sa0[e] + sa1[e]);
            lsum += p[e];
        }
        frag8 pf[2];
#pragma unroll
        for (int g = 0; g < 2; g++) {
            uint4 w;
            w.x = pk2bf(p[g * 8 + 0], p[g * 8 + 1]);
            w.y = pk2bf(p[g * 8 + 2], p[g * 8 + 3]);
            w.z = pk2bf(p[g * 8 + 4], p[g * 8 + 5]);
            w.w = pk2bf(p[g * 8 + 6], p[g * 8 + 7]);
            pf[g] = *(frag8*)&w;
        }
#pragma unroll
        for (int g = 0; g < 2; g++)
#pragma unroll
            for (int nb = 0; nb < 8; nb++) {
                frag8 vf = *(const frag8*)(Vb + (g * 2 + hw) * 2048 + (nb * 32 + l32) * 8);
                acc[nb] = __builtin_amdgcn_mfma_f32_32x32x16_bf16(vf, pf[g], acc[nb], 0, 0, 0);
            }
    };

    prefetch(0, 0);
    __syncthreads();
    for (int kt = 0; kt < 30; kt += 2) {
        prefetch(1, kt + 1);
        body(&Ks[0][0], &Vs[0][0]);
        __syncthreads();
        prefetch(0, kt + 2);
        body(&Ks[1][0], &Vs[1][0]);
        __syncthreads();
    }
    prefetch(1, 31);
    body(&Ks[0][0], &Vs[0][0]);
    __syncthreads();
    body(&Ks[1][0], &Vs[1][0]);

    lsum += __shfl_xor(lsum, 32);
    const float li = 1.f / lsum;          // col l32 = q-row = this lane's row

    unsigned short* opan = ob + ((size_t)bh * 32 + qt * 4 + wave) * TSH;
#pragma unroll
    for (int nb = 0; nb < 8; nb++)
#pragma unroll
        for (int G = 0; G < 4; G++) {
            unsigned short* cell = opan + ((nb * 4 + G) * 32 + l32) * 8 + 4 * hw;
            uint2 st;
            st.x = pk2bf(acc[nb][4 * G + 0] * li, acc[nb][4 * G + 1] * li);
            st.y = pk2bf(acc[nb][4 * G + 2] * li, acc[nb][4 * G + 3] * li);
            *(uint2*)cell = st;
        }
}

// ---------------------------------------------------------------------------
// K3: out = O @ Wo + bo + xt. 8-wave blocks (512 thr), 64ch x 128tok, BK=64,
// dbuf 48 KB, 2048 waves = 2 waves/SIMD (was 1). Wave = 32ch x 32tok, acc[1].
// ---------------------------------------------------------------------------
__global__ __launch_bounds__(512) void k3_proj(
    const unsigned short* __restrict__ Ob, const unsigned short* __restrict__ WotT,
    const float* __restrict__ bo, const float* __restrict__ x,
    float* __restrict__ out)
{
    __shared__ unsigned short As[2][4096];   // 2 ch panels x 2 KB-per-32k x 2 (BK=64)
    __shared__ unsigned short Bs[2][8192];   // 4 token panels
    const int t = threadIdx.x;
    const int wave = t >> 6, lane = t & 63;
    const int l32 = lane & 31, hw = lane >> 5;
    const int wc = wave & 1, wt = wave >> 1;       // ch half, token panel
    const int c0 = blockIdx.x * 64, m0 = blockIdx.y * 128;
    const int b = m0 >> 10, s0 = m0 & 1023;

    const unsigned short* Ag = WotT + (size_t)(c0 >> 5) * 65536;

    f32x16 acc;
#pragma unroll
    for (int r = 0; r < 16; r++) acc[r] = 0.f;

    auto stage = [&](int buf, int kt) {            // kt in 0..31, BK=64
        const int hh = kt >> 2, lc = (kt & 3) * 8; // head, local kchunk base
#pragma unroll
        for (int j = 0; j < 3; j++) {
            int rgn = wave * 3 + j;                // 24 regions of 1 KB
            if (rgn < 8) {
                int wp = rgn >> 2, q4 = rgn & 3;
                load_lds16(Ag + (size_t)wp * 65536 + kt * 2048 + q4 * 512 + lane * 8,
                           &As[buf][wp * 2048 + q4 * 512]);
            } else {
                int r2 = rgn - 8, p = r2 >> 2, q4 = r2 & 3;
                load_lds16(Ob + (size_t)((b * NH + hh) * 32 + (s0 >> 5) + p) * TSH
                               + lc * 256 + q4 * 512 + lane * 8,
                           &Bs[buf][p * 2048 + q4 * 512]);
            }
        }
    };

    auto body = [&](const unsigned short* Ab, const unsigned short* Bb) {
#pragma unroll
        for (int t2 = 0; t2 < 4; t2++) {
            frag8 af = *(const frag8*)(Ab + wc * 2048 + (2 * t2 + hw) * 256 + l32 * 8);
            frag8 bf = *(const frag8*)(Bb + wt * 2048 + (2 * t2 + hw) * 256 + l32 * 8);
            acc = __builtin_amdgcn_mfma_f32_32x32x16_bf16(af, bf, acc, 0, 0, 0);
        }
    };

    stage(0, 0);
    __syncthreads();
    for (int kt = 0; kt < 30; kt += 2) {
        stage(1, kt + 1); body(&As[0][0], &Bs[0][0]); __syncthreads();
        stage(0, kt + 2); body(&As[1][0], &Bs[1][0]); __syncthreads();
    }
    stage(1, 31); body(&As[0][0], &Bs[0][0]); __syncthreads();
    body(&As[1][0], &Bs[1][0]);

    // D: col l32 = token, reg r -> ch-local = 4hw + (r&3) + 8*(r>>2)
    const int s = s0 + wt * 32 + l32;
#pragma unroll
    for (int G = 0; G < 4; G++) {
        float4 bb = *(const float4*)(&bo[c0 + wc * 32 + 4 * hw + 8 * G]);
#pragma unroll
        for (int e = 0; e < 4; e++) {
            const int ch = c0 + wc * 32 + 4 * hw + 8 * G + e;
            const float bbe = (e == 0) ? bb.x : (e == 1) ? bb.y : (e == 2) ? bb.z : bb.w;
            size_t off = (size_t)(b * 256 + ch) * 1024 + s;
            out[off] = acc[4 * G + e] + bbe + x[off];
        }
    }
}

// ---------------------------------------------------------------------------
extern "C" void kernel_launch(void* const* d_in, const int* in_sizes, int n_in,
                              void* d_out, int out_size, void* d_ws, size_t ws_size,
                              hipStream_t stream)
{
    const float* x  = (const float*)d_in[0];
    const float* Wp = (const float*)d_in[1];
    const float* bp = (const float*)d_in[2];
    const float* Wo = (const float*)d_in[3];
    const float* bo = (const float*)d_in[4];
    float* out = (float*)d_out;

    char* ws = (char*)d_ws;
    unsigned short* qb   = (unsigned short*)(ws);                // T32; O overwrites
    unsigned short* kb   = (unsigned short*)(ws + 33554432);     // T32
    unsigned short* vb   = (unsigned short*)(ws + 67108864);     // key-permuted tiles
    unsigned short* xbT  = (unsigned short*)(ws + 100663296);    // T32 panels
    unsigned short* WptT = (unsigned short*)(ws + 104857600);    // T32 192 panels
    unsigned short* WotT = (unsigned short*)(ws + 108003328);    // T32 8 panels (K=2048)

    k0_all<<<dim3(4096), 256, 0, stream>>>(x, xbT, Wp, WptT, Wo, WotT);
    k1_qkv<<<dim3(48, 32), 256, 0, stream>>>(xbT, WptT, bp, qb, kb, vb);
    k2_attn<<<dim3(512), 256, 0, stream>>>(qb, kb, vb, qb /* O over Q */);
    k3_proj<<<dim3(4, 64), 512, 0, stream>>>(qb, WotT, bo, x, out);
}

// Round 11
// 221.026 us; speedup vs baseline: 1.0387x; 1.0387x over previous
//
#include <hip/hip_runtime.h>

// B=8, C=256, H=W=32 -> S=1024; NH=8, DK=256; qkv dim 6144.
#define NH    8
#define DK    256
#define SS    1024
// q is pre-scaled by SCALE*log2(e) in k1 so softmax runs in exp2 domain.
#define QSCALE 0.09016844136947155f   // (1/16) * 1.4426950408889634
#define TSH   8192                    // shorts per 16 KB tile (32 rows x 256 k)

using frag8  = __attribute__((ext_vector_type(8))) short;   // 8 bf16 (4 VGPRs)
using f32x16 = __attribute__((ext_vector_type(16))) float;  // 32x32 MFMA acc

__device__ __forceinline__ unsigned short f2bf(float f) {
    unsigned int u = __float_as_uint(f);
    return (unsigned short)((u + 0x7FFFu + ((u >> 16) & 1u)) >> 16);   // RNE
}
__device__ __forceinline__ unsigned int pk2bf(float lo, float hi) {
    unsigned int ul = __float_as_uint(lo), uh = __float_as_uint(hi);
    ul += 0x7FFFu + ((ul >> 16) & 1u);
    uh += 0x7FFFu + ((uh >> 16) & 1u);
    return (ul >> 16) | (uh & 0xFFFF0000u);
}

// async global->LDS, 16B/lane; LDS dest = wave-uniform base + lane*16.
__device__ __forceinline__ void load_lds16(const void* g, void* l) {
    __builtin_amdgcn_global_load_lds(
        (const __attribute__((address_space(1))) unsigned int*)g,
        (__attribute__((address_space(3))) unsigned int*)l, 16, 0, 0);
}

// T32 format: panel = 32 rows x K cols; cell(row r, kchunk c) = 8 shorts at
// (c*32 + r)*8. Frag reads are 64 consecutive 16B cells (conflict-free).
// q/k: T32 panels (rows=tokens, cols=d). v: key-permuted tiles (chunk g*2+hw,
// position j holds key 16g+4hw+(j&3)+8*(j>>2)). O (over qb): q/k T32 format.

// ---------------------------------------------------------------------------
// K0: x, Wp, Wo  fp32 -> bf16 T32 panels, one launch. (r10 verbatim)
// ---------------------------------------------------------------------------
__global__ __launch_bounds__(256) void k0_all(
    const float* __restrict__ x,  unsigned short* __restrict__ xbT,
    const float* __restrict__ Wp, unsigned short* __restrict__ WptT,
    const float* __restrict__ Wo, unsigned short* __restrict__ WotT)
{
    __shared__ float tile[32][33];
    const int bid = blockIdx.x;
    const float* in; unsigned short* outp; int C, c0, r0; size_t pbase; int psz;
    if (bid < 2048) {            // x[8][256][1024]: k=channel(256), n=s(1024)
        int rr = bid;
        int b = rr >> 8;
        in = x + (size_t)b * 256 * 1024;
        C = 1024; c0 = (rr & 31) * 32; r0 = ((rr >> 5) & 7) * 32;
        psz = 8192; pbase = (size_t)(b * 32 + (c0 >> 5)); outp = xbT;
    } else if (bid < 3584) {     // Wp[256][6144]: k=256, n=6144
        int rr = bid - 2048;
        in = Wp; C = 6144; c0 = (rr % 192) * 32; r0 = (rr / 192) * 32;
        psz = 8192; pbase = (size_t)(c0 >> 5); outp = WptT;
    } else {                     // Wo[2048][256]: k=2048, n=256
        int rr = bid - 3584;
        in = Wo; C = 256; c0 = (rr & 7) * 32; r0 = (rr >> 3) * 32;
        psz = 65536; pbase = (size_t)(c0 >> 5); outp = WotT;
    }
    const int tx = threadIdx.x & 31, ty = threadIdx.x >> 5;
#pragma unroll
    for (int j = 0; j < 4; j++)
        tile[ty + j * 8][tx] = in[(size_t)(r0 + ty + j * 8) * C + c0 + tx];
    __syncthreads();
    const int k = r0 + tx;
    unsigned short* dst = outp + pbase * psz + ((k >> 3) * 32) * 8 + (k & 7);
#pragma unroll
    for (int j = 0; j < 4; j++)
        dst[(ty + j * 8) * 8] = f2bf(tile[tx][ty + j * 8]);
}

// ---------------------------------------------------------------------------
// K1: qkv = xt @ Wp + bp. 32x32x16 MFMA, T32, conflict-free, dbuf.
// 128 dims x 128 tokens per block, grid (48,64) -> 12 waves/SIMD
// oversubscription (r9 verbatim — the best-measured k1 config).
// ---------------------------------------------------------------------------
__global__ __launch_bounds__(256) void k1_qkv(
    const unsigned short* __restrict__ xbT, const unsigned short* __restrict__ WptT,
    const float* __restrict__ bp,
    unsigned short* __restrict__ qb, unsigned short* __restrict__ kb,
    unsigned short* __restrict__ vb)
{
    __shared__ unsigned short Xs[2][4096];   // 4 token panels x 1 KB per kt
    __shared__ unsigned short Ws[2][4096];   // 4 dim panels
    const int t = threadIdx.x;
    const int wave = t >> 6, lane = t & 63;
    const int l32 = lane & 31, hw = lane >> 5;
    const int n0 = blockIdx.x * 128, m0 = blockIdx.y * 128;
    const int b = m0 >> 10, s0 = m0 & 1023;

    const int h = n0 / 768;
    const int rem = n0 - h * 768;
    const int tt = rem >> 8;                  // 0=q 1=k 2=v (block-uniform)
    const int dcol0 = rem & 255;

    const unsigned short* Xg = xbT + (size_t)(b * 32 + (s0 >> 5)) * TSH;
    const unsigned short* Wg = WptT + (size_t)(n0 >> 5) * TSH;

    f32x16 acc[4];
#pragma unroll
    for (int j = 0; j < 4; j++)
#pragma unroll
        for (int r = 0; r < 16; r++) acc[j][r] = 0.f;

    auto stage = [&](int buf, int kt) {
#pragma unroll
        for (int j = 0; j < 4; j++) {
            int rgn = wave * 4 + j;           // 16 regions of 1 KB
            if (rgn < 8) {
                int p = rgn >> 1, half = rgn & 1;
                load_lds16(Xg + (size_t)p * TSH + kt * 1024 + half * 512 + lane * 8,
                           &Xs[buf][p * 1024 + half * 512]);
            } else {
                int r2 = rgn - 8, p = r2 >> 1, half = r2 & 1;
                load_lds16(Wg + (size_t)p * TSH + kt * 1024 + half * 512 + lane * 8,
                           &Ws[buf][p * 1024 + half * 512]);
            }
        }
    };

    stage(0, 0);
    __syncthreads();

    for (int kt = 0; kt < 8; kt++) {
        const int cur = kt & 1;
        if (kt < 7) stage(cur ^ 1, kt + 1);
        const unsigned short* Fa = (tt < 2) ? &Ws[cur][wave * 1024] : &Xs[cur][wave * 1024];
        const unsigned short* Fb = (tt < 2) ? &Xs[cur][0] : &Ws[cur][0];
#pragma unroll
        for (int t2 = 0; t2 < 2; t2++) {
            frag8 af = *(const frag8*)(Fa + (2 * t2 + hw) * 256 + l32 * 8);
#pragma unroll
            for (int j = 0; j < 4; j++) {
                frag8 bf = *(const frag8*)(Fb + j * 1024 + (2 * t2 + hw) * 256 + l32 * 8);
                acc[j] = __builtin_amdgcn_mfma_f32_32x32x16_bf16(af, bf, acc[j], 0, 0, 0);
            }
        }
        __syncthreads();
    }

    if (tt < 2) {
        // D: col l32 = token (panel j), reg r -> d-local = 4hw + (r&3) + 8*(r>>2)
        const float sc = (tt == 0) ? QSCALE : 1.0f;
        unsigned short* dst0 = (tt == 0 ? qb : kb);
        const int dc0 = (dcol0 + wave * 32) >> 3;     // base dchunk
#pragma unroll
        for (int G = 0; G < 4; G++) {
            float4 bb = *(const float4*)(&bp[n0 + wave * 32 + 4 * hw + 8 * G]);
#pragma unroll
            for (int j = 0; j < 4; j++) {
                unsigned short* cell = dst0
                    + (size_t)((b * NH + h) * 32 + (s0 >> 5) + j) * TSH
                    + ((dc0 + G) * 32 + l32) * 8 + 4 * hw;
                uint2 st;
                st.x = pk2bf((acc[j][4 * G + 0] + bb.x) * sc, (acc[j][4 * G + 1] + bb.y) * sc);
                st.y = pk2bf((acc[j][4 * G + 2] + bb.z) * sc, (acc[j][4 * G + 3] + bb.w) * sc);
                *(uint2*)cell = st;
            }
        }
    } else {
        // D: col l32 = v-dim (panel j), reg r -> key-local = 4hw + (r&3) + 8*(r>>2)
        unsigned short* vt = vb + (size_t)((b * NH + h) * 32 + (s0 >> 5) + wave) * TSH;
#pragma unroll
        for (int j = 0; j < 4; j++) {
            const int d = dcol0 + j * 32 + l32;
            const float bv = bp[n0 + j * 32 + l32];
#pragma unroll
            for (int G = 0; G < 4; G++) {
                int g = G >> 1;
                unsigned short* cell = vt + (g * 2 + hw) * 2048 + d * 8 + 4 * (G & 1);
                uint2 st;
                st.x = pk2bf(acc[j][4 * G + 0] + bv, acc[j][4 * G + 1] + bv);
                st.y = pk2bf(acc[j][4 * G + 2] + bv, acc[j][4 * G + 3] + bv);
                *(uint2*)cell = st;
            }
        }
    }
}

// ---------------------------------------------------------------------------
// K2: attention (r10 verbatim). K-loop unrolled x2 with compile-time buffer
// pointers; last iter peeled. PV A=vf, B=pf -> coalesced T32 O epilogue.
// ---------------------------------------------------------------------------
__global__ __launch_bounds__(256, 2) void k2_attn(
    const unsigned short* __restrict__ qb, const unsigned short* __restrict__ kb,
    const unsigned short* __restrict__ vb, unsigned short* __restrict__ ob)
{
    __shared__ unsigned short Ks[2][TSH];
    __shared__ unsigned short Vs[2][TSH];

    const int t = threadIdx.x;
    const int wave = t >> 6, lane = t & 63;
    const int l32 = lane & 31, hw = lane >> 5;

    const int flat = blockIdx.x;
    const int xcd = flat & 7, tt2 = flat >> 3;
    const int qt = tt2 & 7;
    const int bh = xcd * 8 + (tt2 >> 3);

    frag8 qf[16];
    {
        const unsigned short* qp = qb + ((size_t)bh * 32 + qt * 4 + wave) * TSH
                                 + hw * 256 + l32 * 8;
#pragma unroll
        for (int s = 0; s < 16; s++) qf[s] = *(const frag8*)(qp + s * 512);
    }

    f32x16 acc[8];
#pragma unroll
    for (int nb = 0; nb < 8; nb++)
#pragma unroll
        for (int r = 0; r < 16; r++) acc[nb][r] = 0.f;
    float lsum = 0.f;

    const unsigned short* kstg = kb + (size_t)bh * 32 * TSH + wave * 2048 + lane * 8;
    const unsigned short* vstg = vb + (size_t)bh * 32 * TSH + wave * 2048 + lane * 8;

    auto prefetch = [&](int buf, int kt) {
#pragma unroll
        for (int j = 0; j < 4; j++) {
            load_lds16(kstg + (size_t)kt * TSH + j * 512, &Ks[buf][wave * 2048 + j * 512]);
            load_lds16(vstg + (size_t)kt * TSH + j * 512, &Vs[buf][wave * 2048 + j * 512]);
        }
    };

    auto body = [&](const unsigned short* Kb, const unsigned short* Vb) {
        f32x16 sa0, sa1;
#pragma unroll
        for (int r = 0; r < 16; r++) { sa0[r] = 0.f; sa1[r] = 0.f; }
#pragma unroll
        for (int s = 0; s < 16; s += 2) {
            frag8 kf0 = *(const frag8*)(Kb + (2 * s + hw) * 256 + l32 * 8);
            frag8 kf1 = *(const frag8*)(Kb + (2 * s + 2 + hw) * 256 + l32 * 8);
            sa0 = __builtin_amdgcn_mfma_f32_32x32x16_bf16(kf0, qf[s], sa0, 0, 0, 0);
            sa1 = __builtin_amdgcn_mfma_f32_32x32x16_bf16(kf1, qf[s + 1], sa1, 0, 0, 0);
        }
        float p[16];
#pragma unroll
        for (int e = 0; e < 16; e++) {
            p[e] = exp2f(sa0[e] + sa1[e]);
            lsum += p[e];
        }
        frag8 pf[2];
#pragma unroll
        for (int g = 0; g < 2; g++) {
            uint4 w;
            w.x = pk2bf(p[g * 8 + 0], p[g * 8 + 1]);
            w.y = pk2bf(p[g * 8 + 2], p[g * 8 + 3]);
            w.z = pk2bf(p[g * 8 + 4], p[g * 8 + 5]);
            w.w = pk2bf(p[g * 8 + 6], p[g * 8 + 7]);
            pf[g] = *(frag8*)&w;
        }
#pragma unroll
        for (int g = 0; g < 2; g++)
#pragma unroll
            for (int nb = 0; nb < 8; nb++) {
                frag8 vf = *(const frag8*)(Vb + (g * 2 + hw) * 2048 + (nb * 32 + l32) * 8);
                acc[nb] = __builtin_amdgcn_mfma_f32_32x32x16_bf16(vf, pf[g], acc[nb], 0, 0, 0);
            }
    };

    prefetch(0, 0);
    __syncthreads();
    for (int kt = 0; kt < 30; kt += 2) {
        prefetch(1, kt + 1);
        body(&Ks[0][0], &Vs[0][0]);
        __syncthreads();
        prefetch(0, kt + 2);
        body(&Ks[1][0], &Vs[1][0]);
        __syncthreads();
    }
    prefetch(1, 31);
    body(&Ks[0][0], &Vs[0][0]);
    __syncthreads();
    body(&Ks[1][0], &Vs[1][0]);

    lsum += __shfl_xor(lsum, 32);
    const float li = 1.f / lsum;          // col l32 = q-row = this lane's row

    unsigned short* opan = ob + ((size_t)bh * 32 + qt * 4 + wave) * TSH;
#pragma unroll
    for (int nb = 0; nb < 8; nb++)
#pragma unroll
        for (int G = 0; G < 4; G++) {
            unsigned short* cell = opan + ((nb * 4 + G) * 32 + l32) * 8 + 4 * hw;
            uint2 st;
            st.x = pk2bf(acc[nb][4 * G + 0] * li, acc[nb][4 * G + 1] * li);
            st.y = pk2bf(acc[nb][4 * G + 2] * li, acc[nb][4 * G + 3] * li);
            *(uint2*)cell = st;
        }
}

// ---------------------------------------------------------------------------
// K3: out = O @ Wo + bo + xt. (r10 verbatim) 8-wave blocks, 64ch x 128tok,
// BK=64, dbuf, 2048 waves = 2 waves/SIMD. Wave = 32ch x 32tok.
// ---------------------------------------------------------------------------
__global__ __launch_bounds__(512) void k3_proj(
    const unsigned short* __restrict__ Ob, const unsigned short* __restrict__ WotT,
    const float* __restrict__ bo, const float* __restrict__ x,
    float* __restrict__ out)
{
    __shared__ unsigned short As[2][4096];
    __shared__ unsigned short Bs[2][8192];
    const int t = threadIdx.x;
    const int wave = t >> 6, lane = t & 63;
    const int l32 = lane & 31, hw = lane >> 5;
    const int wc = wave & 1, wt = wave >> 1;
    const int c0 = blockIdx.x * 64, m0 = blockIdx.y * 128;
    const int b = m0 >> 10, s0 = m0 & 1023;

    const unsigned short* Ag = WotT + (size_t)(c0 >> 5) * 65536;

    f32x16 acc;
#pragma unroll
    for (int r = 0; r < 16; r++) acc[r] = 0.f;

    auto stage = [&](int buf, int kt) {            // kt in 0..31, BK=64
        const int hh = kt >> 2, lc = (kt & 3) * 8;
#pragma unroll
        for (int j = 0; j < 3; j++) {
            int rgn = wave * 3 + j;                // 24 regions of 1 KB
            if (rgn < 8) {
                int wp = rgn >> 2, q4 = rgn & 3;
                load_lds16(Ag + (size_t)wp * 65536 + kt * 2048 + q4 * 512 + lane * 8,
                           &As[buf][wp * 2048 + q4 * 512]);
            } else {
                int r2 = rgn - 8, p = r2 >> 2, q4 = r2 & 3;
                load_lds16(Ob + (size_t)((b * NH + hh) * 32 + (s0 >> 5) + p) * TSH
                               + lc * 256 + q4 * 512 + lane * 8,
                           &Bs[buf][p * 2048 + q4 * 512]);
            }
        }
    };

    auto body = [&](const unsigned short* Ab, const unsigned short* Bb) {
#pragma unroll
        for (int t2 = 0; t2 < 4; t2++) {
            frag8 af = *(const frag8*)(Ab + wc * 2048 + (2 * t2 + hw) * 256 + l32 * 8);
            frag8 bf = *(const frag8*)(Bb + wt * 2048 + (2 * t2 + hw) * 256 + l32 * 8);
            acc = __builtin_amdgcn_mfma_f32_32x32x16_bf16(af, bf, acc, 0, 0, 0);
        }
    };

    stage(0, 0);
    __syncthreads();
    for (int kt = 0; kt < 30; kt += 2) {
        stage(1, kt + 1); body(&As[0][0], &Bs[0][0]); __syncthreads();
        stage(0, kt + 2); body(&As[1][0], &Bs[1][0]); __syncthreads();
    }
    stage(1, 31); body(&As[0][0], &Bs[0][0]); __syncthreads();
    body(&As[1][0], &Bs[1][0]);

    const int s = s0 + wt * 32 + l32;
#pragma unroll
    for (int G = 0; G < 4; G++) {
        float4 bb = *(const float4*)(&bo[c0 + wc * 32 + 4 * hw + 8 * G]);
#pragma unroll
        for (int e = 0; e < 4; e++) {
            const int ch = c0 + wc * 32 + 4 * hw + 8 * G + e;
            const float bbe = (e == 0) ? bb.x : (e == 1) ? bb.y : (e == 2) ? bb.z : bb.w;
            size_t off = (size_t)(b * 256 + ch) * 1024 + s;
            out[off] = acc[4 * G + e] + bbe + x[off];
        }
    }
}

// ---------------------------------------------------------------------------
extern "C" void kernel_launch(void* const* d_in, const int* in_sizes, int n_in,
                              void* d_out, int out_size, void* d_ws, size_t ws_size,
                              hipStream_t stream)
{
    const float* x  = (const float*)d_in[0];
    const float* Wp = (const float*)d_in[1];
    const float* bp = (const float*)d_in[2];
    const float* Wo = (const float*)d_in[3];
    const float* bo = (const float*)d_in[4];
    float* out = (float*)d_out;

    char* ws = (char*)d_ws;
    unsigned short* qb   = (unsigned short*)(ws);                // T32; O overwrites
    unsigned short* kb   = (unsigned short*)(ws + 33554432);     // T32
    unsigned short* vb   = (unsigned short*)(ws + 67108864);     // key-permuted tiles
    unsigned short* xbT  = (unsigned short*)(ws + 100663296);    // T32 panels
    unsigned short* WptT = (unsigned short*)(ws + 104857600);    // T32 192 panels
    unsigned short* WotT = (unsigned short*)(ws + 108003328);    // T32 8 panels (K=2048)

    k0_all<<<dim3(4096), 256, 0, stream>>>(x, xbT, Wp, WptT, Wo, WotT);
    k1_qkv<<<dim3(48, 64), 256, 0, stream>>>(xbT, WptT, bp, qb, kb, vb);
    k2_attn<<<dim3(512), 256, 0, stream>>>(qb, kb, vb, qb /* O over Q */);
    k3_proj<<<dim3(4, 64), 512, 0, stream>>>(qb, WotT, bo, x, out);
}